// Round 8
// baseline (401.593 us; speedup 1.0000x reference)
//
#include <hip/hip_runtime.h>

#define B_ 128
#define T_ 256
#define H_ 768
#define K_ 64
#define BT_ (B_ * T_)

// ---------------------------------------------------------------------------
// DPP helpers: wave-wide max in ~6 VALU ops (row_shr/bcast ladder).
// ---------------------------------------------------------------------------
template <int CTRL>
__device__ __forceinline__ float dpp_mov_f(float x) {
    return __int_as_float(__builtin_amdgcn_update_dpp(
        __float_as_int(x), __float_as_int(x), CTRL, 0xF, 0xF, false));
}
__device__ __forceinline__ float wave_max64(float x) {
    x = fmaxf(x, dpp_mov_f<0x111>(x));  // row_shr:1
    x = fmaxf(x, dpp_mov_f<0x112>(x));  // row_shr:2
    x = fmaxf(x, dpp_mov_f<0x114>(x));  // row_shr:4
    x = fmaxf(x, dpp_mov_f<0x118>(x));  // row_shr:8
    x = fmaxf(x, dpp_mov_f<0x142>(x));  // row_bcast:15
    x = fmaxf(x, dpp_mov_f<0x143>(x));  // row_bcast:31
    return __int_as_float(__builtin_amdgcn_readlane(__float_as_int(x), 63));
}
__device__ __forceinline__ float readlane0_f(float x) {
    return __int_as_float(__builtin_amdgcn_readfirstlane(__float_as_int(x)));
}

// ---------------------------------------------------------------------------
// Kernel A: emissions = hidden @ W + b  (unchanged from round 4)
// ---------------------------------------------------------------------------
#define BK_ 32
#define P_ 130
__global__ __launch_bounds__(256) void gemm_emis(const float* __restrict__ hidden,
                                                 const float* __restrict__ W,
                                                 const float* __restrict__ bias,
                                                 float* __restrict__ emis) {
    __shared__ float At[BK_ * P_];

    const int tid = threadIdx.x;
    const int lane = tid & 63;
    const int wc = __builtin_amdgcn_readfirstlane((tid >> 6) * 16);
    const int rowbase = blockIdx.x * 128;
    const int srow = tid >> 3;
    const int sh4 = tid & 7;

    float acc0[16], acc1[16];
#pragma unroll
    for (int c = 0; c < 16; ++c) { acc0[c] = bias[wc + c]; acc1[c] = acc0[c]; }

    float4 pf[4];
#pragma unroll
    for (int i = 0; i < 4; ++i)
        pf[i] = *(const float4*)&hidden[(rowbase + srow + i * 32) * H_ + sh4 * 4];

    for (int kb = 0; kb < H_ / BK_; ++kb) {
        __syncthreads();
#pragma unroll
        for (int i = 0; i < 4; ++i) {
            int row = srow + i * 32;
            At[(sh4 * 4 + 0) * P_ + row] = pf[i].x;
            At[(sh4 * 4 + 1) * P_ + row] = pf[i].y;
            At[(sh4 * 4 + 2) * P_ + row] = pf[i].z;
            At[(sh4 * 4 + 3) * P_ + row] = pf[i].w;
        }
        __syncthreads();
        if (kb + 1 < H_ / BK_) {
#pragma unroll
            for (int i = 0; i < 4; ++i)
                pf[i] = *(const float4*)&hidden[(rowbase + srow + i * 32) * H_ +
                                                (kb + 1) * BK_ + sh4 * 4];
        }
        const float* Wk = &W[(kb * BK_) * K_ + wc];
#pragma unroll 8
        for (int h = 0; h < BK_; ++h) {
            float2 a = *(const float2*)&At[h * P_ + 2 * lane];
            float4 w0 = *(const float4*)&Wk[h * K_ + 0];
            float4 w1 = *(const float4*)&Wk[h * K_ + 4];
            float4 w2 = *(const float4*)&Wk[h * K_ + 8];
            float4 w3 = *(const float4*)&Wk[h * K_ + 12];
            acc0[0]  += a.x * w0.x; acc1[0]  += a.y * w0.x;
            acc0[1]  += a.x * w0.y; acc1[1]  += a.y * w0.y;
            acc0[2]  += a.x * w0.z; acc1[2]  += a.y * w0.z;
            acc0[3]  += a.x * w0.w; acc1[3]  += a.y * w0.w;
            acc0[4]  += a.x * w1.x; acc1[4]  += a.y * w1.x;
            acc0[5]  += a.x * w1.y; acc1[5]  += a.y * w1.y;
            acc0[6]  += a.x * w1.z; acc1[6]  += a.y * w1.z;
            acc0[7]  += a.x * w1.w; acc1[7]  += a.y * w1.w;
            acc0[8]  += a.x * w2.x; acc1[8]  += a.y * w2.x;
            acc0[9]  += a.x * w2.y; acc1[9]  += a.y * w2.y;
            acc0[10] += a.x * w2.z; acc1[10] += a.y * w2.z;
            acc0[11] += a.x * w2.w; acc1[11] += a.y * w2.w;
            acc0[12] += a.x * w3.x; acc1[12] += a.y * w3.x;
            acc0[13] += a.x * w3.y; acc1[13] += a.y * w3.y;
            acc0[14] += a.x * w3.z; acc1[14] += a.y * w3.z;
            acc0[15] += a.x * w3.w; acc1[15] += a.y * w3.w;
        }
    }

    float* e0 = &emis[(size_t)(rowbase + 2 * lane) * K_ + wc];
    float* e1 = &emis[(size_t)(rowbase + 2 * lane + 1) * K_ + wc];
#pragma unroll
    for (int q = 0; q < 4; ++q) {
        *(float4*)&e0[q * 4] = make_float4(acc0[q * 4], acc0[q * 4 + 1],
                                           acc0[q * 4 + 2], acc0[q * 4 + 3]);
        *(float4*)&e1[q * 4] = make_float4(acc1[q * 4], acc1[q * 4 + 1],
                                           acc1[q * 4 + 2], acc1[q * 4 + 3]);
    }
}

// ---------------------------------------------------------------------------
// Kernel B: fused CRF. 128 blocks x 128 thr (2 waves). All-to-all via
// v_readlane with asm-pinned schedule (producer->consumer distance >= 4-8
// instrs to cover the VALU-writes-SGPR hazard). ALL asm outputs are
// EARLYCLOBBER (=&) — round 7's plain "=v" let the allocator alias an
// output with a later-read input (Tcol), corrupting the Viterbi scores.
// ---------------------------------------------------------------------------
__global__ __launch_bounds__(128, 1) void crf_kernel(const float* __restrict__ emis,
                                                     const int* __restrict__ masks,
                                                     const int* __restrict__ target,
                                                     const float* __restrict__ trans,
                                                     float* __restrict__ out) {
    __shared__ __align__(16) float ebuf[T_ * K_];   // 64 KB emissions for batch b
    __shared__ __align__(16) float vbuf[T_ * K_];   // 64 KB viterbi v-history
    __shared__ float tbuf[K_ * 65];                 // padded trans rows (backtrack)

    const int tid = threadIdx.x;
    const int lane = tid & 63;
    const int b = blockIdx.x;
    const float* eb = emis + (size_t)b * (T_ * K_);

    {
        const float4* src = (const float4*)eb;
        float4* dst = (float4*)ebuf;
#pragma unroll
        for (int k = 0; k < 32; ++k) dst[tid + k * 128] = src[tid + k * 128];
    }
    int sl = 0;
#pragma unroll
    for (int k = 0; k < 4; ++k) sl += masks[b * T_ + lane + k * 64];
#pragma unroll
    for (int m = 32; m; m >>= 1) sl += __shfl_xor(sl, m, 64);
    const int seq_len = sl;
    __syncthreads();

    if (tid < 64) {
        // ================= forward (wave 0), delayed normalization ==========
        float Ecol[64];
#pragma unroll
        for (int i = 0; i < 64; ++i) Ecol[i] = __expf(trans[i * K_ + lane]);

        float e_c = ebuf[lane];
        float e00 = readlane0_f(e_c);
        float p = __expf(e_c - e00);
        float C = e00;
        float logD0prev = 0.f;
        float e_n = ebuf[K_ + lane];
        float en0 = readlane0_f(e_n);
        float xg = __expf(e_n - en0);

// 8 readlanes back-to-back, then 8 fmacs (sgpr consumed 8 instrs later).
// acc mapping identical to R6: a_k accumulates i == k (mod 8).
// All outputs earlyclobber: asm writes outputs before last input read.
#define FWDG(L0,L1,L2,L3,L4,L5,L6,L7) do {                                   \
        int t0,t1,t2,t3,t4,t5,t6,t7;                                         \
        asm volatile(                                                        \
            "v_readlane_b32 %0, %16, " #L0 "\n\t"                            \
            "v_readlane_b32 %1, %16, " #L1 "\n\t"                            \
            "v_readlane_b32 %2, %16, " #L2 "\n\t"                            \
            "v_readlane_b32 %3, %16, " #L3 "\n\t"                            \
            "v_readlane_b32 %4, %16, " #L4 "\n\t"                            \
            "v_readlane_b32 %5, %16, " #L5 "\n\t"                            \
            "v_readlane_b32 %6, %16, " #L6 "\n\t"                            \
            "v_readlane_b32 %7, %16, " #L7 "\n\t"                            \
            "v_fmac_f32 %8,  %0, %17\n\t"                                    \
            "v_fmac_f32 %9,  %1, %18\n\t"                                    \
            "v_fmac_f32 %10, %2, %19\n\t"                                    \
            "v_fmac_f32 %11, %3, %20\n\t"                                    \
            "v_fmac_f32 %12, %4, %21\n\t"                                    \
            "v_fmac_f32 %13, %5, %22\n\t"                                    \
            "v_fmac_f32 %14, %6, %23\n\t"                                    \
            "v_fmac_f32 %15, %7, %24\n\t"                                    \
            : "=&s"(t0),"=&s"(t1),"=&s"(t2),"=&s"(t3),                       \
              "=&s"(t4),"=&s"(t5),"=&s"(t6),"=&s"(t7),                       \
              "+v"(a0),"+v"(a1),"+v"(a2),"+v"(a3),                           \
              "+v"(a4),"+v"(a5),"+v"(a6),"+v"(a7)                            \
            : "v"(p),                                                        \
              "v"(Ecol[L0]),"v"(Ecol[L1]),"v"(Ecol[L2]),"v"(Ecol[L3]),       \
              "v"(Ecol[L4]),"v"(Ecol[L5]),"v"(Ecol[L6]),"v"(Ecol[L7]));      \
} while (0)

        for (int t = 1; t < T_; ++t) {
            float e_f = (t < T_ - 1) ? ebuf[(t + 1) * K_ + lane] : 0.f;
            float a0 = 0.f, a1 = 0.f, a2 = 0.f, a3 = 0.f;
            float a4 = 0.f, a5 = 0.f, a6 = 0.f, a7 = 0.f;
            FWDG( 0, 1, 2, 3, 4, 5, 6, 7);
            FWDG( 8, 9,10,11,12,13,14,15);
            FWDG(16,17,18,19,20,21,22,23);
            FWDG(24,25,26,27,28,29,30,31);
            FWDG(32,33,34,35,36,37,38,39);
            FWDG(40,41,42,43,44,45,46,47);
            FWDG(48,49,50,51,52,53,54,55);
            FWDG(56,57,58,59,60,61,62,63);
            float D = ((a0 + a1) + (a2 + a3)) + ((a4 + a5) + (a6 + a7));
            float pnew = D * xg;
            if (t < seq_len) { p = pnew; C += en0 + logD0prev; }
            float D0 = readlane0_f(D);
            logD0prev = __logf(D0);
            float gn = __fdividef(1.f, D0);
            en0 = readlane0_f(e_f);
            xg = __expf(e_f - en0) * gn;
            e_n = e_f;
        }
#undef FWDG
        float rs = p;
#pragma unroll
        for (int m = 32; m; m >>= 1) rs += __shfl_xor(rs, m, 64);
        float log_norm = C + __logf(rs);

        float sc = 0.f;
#pragma unroll
        for (int k = 0; k < 4; ++k) {
            int t = lane + k * 64;
            if (t < seq_len) {
                int tg = target[b * T_ + t];
                sc += ebuf[t * K_ + tg];
                if (t >= 1) sc += trans[target[b * T_ + t - 1] * K_ + tg];
            }
        }
#pragma unroll
        for (int m = 32; m; m >>= 1) sc += __shfl_xor(sc, m, 64);
        if (lane == 0) out[BT_ + b] = sc - log_norm;
    } else {
        // ================= Viterbi (wave 1): pinned readlane max-plus =======
        float Tcol[64];
#pragma unroll
        for (int i = 0; i < 64; ++i) Tcol[i] = trans[i * K_ + lane];
        for (int idx = lane; idx < K_ * K_; idx += 64)
            tbuf[(idx >> 6) * 65 + (idx & 63)] = trans[idx];

        float v = ebuf[lane];
        vbuf[lane] = v;
        float e_n = ebuf[K_ + lane];

// 4 readlanes, 4 adds, 4 maxes — sgpr consumed 4 instrs after its producer.
// m mapping identical to R6. All outputs earlyclobber (see header comment).
#define VITG(L0,L1,L2,L3, M0,M1,M2,M3) do {                                  \
        int t0,t1,t2,t3; float u0,u1,u2,u3;                                  \
        asm volatile(                                                        \
            "v_readlane_b32 %0, %12, " #L0 "\n\t"                            \
            "v_readlane_b32 %1, %12, " #L1 "\n\t"                            \
            "v_readlane_b32 %2, %12, " #L2 "\n\t"                            \
            "v_readlane_b32 %3, %12, " #L3 "\n\t"                            \
            "v_add_f32 %4, %0, %13\n\t"                                      \
            "v_add_f32 %5, %1, %14\n\t"                                      \
            "v_add_f32 %6, %2, %15\n\t"                                      \
            "v_add_f32 %7, %3, %16\n\t"                                      \
            "v_max_f32 %8,  %8,  %4\n\t"                                     \
            "v_max_f32 %9,  %9,  %5\n\t"                                     \
            "v_max_f32 %10, %10, %6\n\t"                                     \
            "v_max_f32 %11, %11, %7\n\t"                                     \
            : "=&s"(t0),"=&s"(t1),"=&s"(t2),"=&s"(t3),                       \
              "=&v"(u0),"=&v"(u1),"=&v"(u2),"=&v"(u3),                       \
              "+v"(M0),"+v"(M1),"+v"(M2),"+v"(M3)                            \
            : "v"(v),                                                        \
              "v"(Tcol[L0]),"v"(Tcol[L1]),"v"(Tcol[L2]),"v"(Tcol[L3]));      \
} while (0)

        for (int t = 1; t < T_; ++t) {
            float e_f = (t < T_ - 1) ? ebuf[(t + 1) * K_ + lane] : 0.f;
            float m0 = -3.4e38f, m1 = m0, m2 = m0, m3 = m0;
            float m4 = m0, m5 = m0, m6 = m0, m7 = m0;
            VITG( 0, 1, 2, 3, m0,m1,m2,m3);
            VITG( 4, 5, 6, 7, m4,m5,m6,m7);
            VITG( 8, 9,10,11, m0,m1,m2,m3);
            VITG(12,13,14,15, m4,m5,m6,m7);
            VITG(16,17,18,19, m0,m1,m2,m3);
            VITG(20,21,22,23, m4,m5,m6,m7);
            VITG(24,25,26,27, m0,m1,m2,m3);
            VITG(28,29,30,31, m4,m5,m6,m7);
            VITG(32,33,34,35, m0,m1,m2,m3);
            VITG(36,37,38,39, m4,m5,m6,m7);
            VITG(40,41,42,43, m0,m1,m2,m3);
            VITG(44,45,46,47, m4,m5,m6,m7);
            VITG(48,49,50,51, m0,m1,m2,m3);
            VITG(52,53,54,55, m4,m5,m6,m7);
            VITG(56,57,58,59, m0,m1,m2,m3);
            VITG(60,61,62,63, m4,m5,m6,m7);
            float M = fmaxf(fmaxf(fmaxf(m0, m1), fmaxf(m2, m3)),
                            fmaxf(fmaxf(m4, m5), fmaxf(m6, m7)));
            float vn = M + e_n;
            if (t < seq_len) v = vn;
            vbuf[t * K_ + lane] = v;
            e_n = e_f;
        }
#undef VITG

        float M = wave_max64(v);
        unsigned long long ball = __ballot(v >= M);
        int tag = (int)__builtin_ctzll(ball);

        int path[4];
#pragma unroll
        for (int k = 0; k < 4; ++k) path[k] = 0;
        if (lane == ((T_ - 1) & 63)) path[(T_ - 1) >> 6] = tag;

        float vpre = vbuf[(T_ - 2) * K_ + lane];
        for (int t = T_ - 1; t >= 1; --t) {
            float vnext = (t >= 2) ? vbuf[(t - 2) * K_ + lane] : 0.f;
            if (t < seq_len) {
                float s = vpre + tbuf[lane * 65 + tag];
                float Ms = wave_max64(s);
                unsigned long long bl = __ballot(s >= Ms);
                tag = (int)__builtin_ctzll(bl);
            }
            int pidx = t - 1;
            if (lane == (pidx & 63)) path[pidx >> 6] = tag;
            vpre = vnext;
        }
#pragma unroll
        for (int k = 0; k < 4; ++k) {
            int t = lane + k * 64;
            out[b * T_ + t] = (t < seq_len) ? (float)path[k] : 0.f;
        }
    }
}

// ---------------------------------------------------------------------------
extern "C" void kernel_launch(void* const* d_in, const int* in_sizes, int n_in,
                              void* d_out, int out_size, void* d_ws, size_t ws_size,
                              hipStream_t stream) {
    const float* hidden = (const float*)d_in[0];
    const int* masks    = (const int*)d_in[1];
    const int* target   = (const int*)d_in[2];
    const float* W      = (const float*)d_in[3];
    const float* bias   = (const float*)d_in[4];
    const float* trans  = (const float*)d_in[5];
    float* out = (float*)d_out;
    float* emis = (float*)d_ws;

    gemm_emis<<<dim3(BT_ / 128), dim3(256), 0, stream>>>(hidden, W, bias, emis);
    crf_kernel<<<dim3(B_), dim3(128), 0, stream>>>(emis, masks, target, trans, out);
}

// Round 9
// 381.451 us; speedup vs baseline: 1.0528x; 1.0528x over previous
//
#include <hip/hip_runtime.h>

#define B_ 128
#define T_ 256
#define H_ 768
#define K_ 64
#define BT_ (B_ * T_)

// ---------------------------------------------------------------------------
// DPP helpers: wave-wide max in ~6 VALU ops (row_shr/bcast ladder).
// ---------------------------------------------------------------------------
template <int CTRL>
__device__ __forceinline__ float dpp_mov_f(float x) {
    return __int_as_float(__builtin_amdgcn_update_dpp(
        __float_as_int(x), __float_as_int(x), CTRL, 0xF, 0xF, false));
}
__device__ __forceinline__ float wave_max64(float x) {
    x = fmaxf(x, dpp_mov_f<0x111>(x));  // row_shr:1
    x = fmaxf(x, dpp_mov_f<0x112>(x));  // row_shr:2
    x = fmaxf(x, dpp_mov_f<0x114>(x));  // row_shr:4
    x = fmaxf(x, dpp_mov_f<0x118>(x));  // row_shr:8
    x = fmaxf(x, dpp_mov_f<0x142>(x));  // row_bcast:15
    x = fmaxf(x, dpp_mov_f<0x143>(x));  // row_bcast:31
    return __int_as_float(__builtin_amdgcn_readlane(__float_as_int(x), 63));
}
__device__ __forceinline__ float readlane0_f(float x) {
    return __int_as_float(__builtin_amdgcn_readfirstlane(__float_as_int(x)));
}
template <int I>
__device__ __forceinline__ float readlane_f(float x) {
    return __int_as_float(__builtin_amdgcn_readlane(__float_as_int(x), I));
}

// ---------------------------------------------------------------------------
// Kernel A: emissions = hidden @ W + b  (fp32, M=32768, N=64, K=768)
// v3: 512 blocks x 256 thr, 64 rows x 64 cols per block -> 2 blocks/CU,
// 2 waves/SIMD (R4's 1 wave/SIMD exposed all DS/VMEM latency).
// Thread: 2 rows (b64 LDS read) x 8 cols (VMEM W broadcast), 16 fmac/h.
// ---------------------------------------------------------------------------
#define GBK 32
#define GP 66   // At row stride: [h][row], 64 rows + 2 pad (bank-conflict-free)
__global__ __launch_bounds__(256, 2) void gemm_emis(const float* __restrict__ hidden,
                                                    const float* __restrict__ W,
                                                    const float* __restrict__ bias,
                                                    float* __restrict__ emis) {
    __shared__ float At[GBK * GP];   // 8.4 KB

    const int tid = threadIdx.x;
    const int lane = tid & 63;
    const int wv = tid >> 6;          // wave 0..3 -> 16-col group
    const int rp = lane & 31;         // row pair: rows 2rp, 2rp+1
    const int ch = lane >> 5;         // col half within wave group
    const int colbase = wv * 16 + ch * 8;
    const int rowbase = blockIdx.x * 64;
    const int srow = tid >> 3;        // staging row 0..31 (+32 for i=1)
    const int sh4 = tid & 7;          // staging h-quad

    float acc0[8], acc1[8];
#pragma unroll
    for (int c = 0; c < 8; ++c) { acc0[c] = bias[colbase + c]; acc1[c] = acc0[c]; }

    float4 pf[2];
#pragma unroll
    for (int i = 0; i < 2; ++i)
        pf[i] = *(const float4*)&hidden[(size_t)(rowbase + srow + i * 32) * H_ + sh4 * 4];

    for (int kb = 0; kb < H_ / GBK; ++kb) {
        __syncthreads();
#pragma unroll
        for (int i = 0; i < 2; ++i) {
            int row = srow + i * 32;
            At[(sh4 * 4 + 0) * GP + row] = pf[i].x;
            At[(sh4 * 4 + 1) * GP + row] = pf[i].y;
            At[(sh4 * 4 + 2) * GP + row] = pf[i].z;
            At[(sh4 * 4 + 3) * GP + row] = pf[i].w;
        }
        __syncthreads();
        if (kb + 1 < H_ / GBK) {
#pragma unroll
            for (int i = 0; i < 2; ++i)
                pf[i] = *(const float4*)&hidden[(size_t)(rowbase + srow + i * 32) * H_ +
                                                (kb + 1) * GBK + sh4 * 4];
        }
        const float* Wk = &W[(size_t)(kb * GBK) * K_ + colbase];
#pragma unroll 4
        for (int h = 0; h < GBK; ++h) {
            float2 a = *(const float2*)&At[h * GP + 2 * rp];
            float4 w0 = *(const float4*)&Wk[h * K_ + 0];
            float4 w1 = *(const float4*)&Wk[h * K_ + 4];
            acc0[0] += a.x * w0.x; acc1[0] += a.y * w0.x;
            acc0[1] += a.x * w0.y; acc1[1] += a.y * w0.y;
            acc0[2] += a.x * w0.z; acc1[2] += a.y * w0.z;
            acc0[3] += a.x * w0.w; acc1[3] += a.y * w0.w;
            acc0[4] += a.x * w1.x; acc1[4] += a.y * w1.x;
            acc0[5] += a.x * w1.y; acc1[5] += a.y * w1.y;
            acc0[6] += a.x * w1.z; acc1[6] += a.y * w1.z;
            acc0[7] += a.x * w1.w; acc1[7] += a.y * w1.w;
        }
    }

    float* e0 = &emis[(size_t)(rowbase + 2 * rp) * K_ + colbase];
    float* e1 = &emis[(size_t)(rowbase + 2 * rp + 1) * K_ + colbase];
    *(float4*)&e0[0] = make_float4(acc0[0], acc0[1], acc0[2], acc0[3]);
    *(float4*)&e0[4] = make_float4(acc0[4], acc0[5], acc0[6], acc0[7]);
    *(float4*)&e1[0] = make_float4(acc1[0], acc1[1], acc1[2], acc1[3]);
    *(float4*)&e1[4] = make_float4(acc1[4], acc1[5], acc1[6], acc1[7]);
}

// ---------------------------------------------------------------------------
// Kernel B: CRF. 256 blocks x 64 thr (1 wave each; kernel is serial-chain
// LATENCY bound -> only per-step chain latency matters, CUs are plentiful).
// blocks 0..127  : forward log-norm + seq score. ZERO LDS ops in the loop —
//                  emissions read from global with 1-step prefetch (R6's
//                  unexplained ~1000 cyc/step stall correlates with DS ops).
// blocks 128..255: Viterbi. Only an off-chain ds_write (v history) remains.
// Transport of p/v: compiler-scheduled v_readlane (R6 style; R8's asm
// pinning regressed).
// ---------------------------------------------------------------------------
__global__ __launch_bounds__(64, 1) void crf_kernel(const float* __restrict__ emis,
                                                    const int* __restrict__ masks,
                                                    const int* __restrict__ target,
                                                    const float* __restrict__ trans,
                                                    float* __restrict__ out) {
    __shared__ __align__(16) float vbuf[T_ * K_];   // 64 KB (Viterbi blocks)
    __shared__ float tbuf[K_ * 65];                 // padded trans rows (backtrack)

    const int lane = threadIdx.x;
    const int bid = blockIdx.x;
    const int b = bid & (B_ - 1);

    int sl = 0;
#pragma unroll
    for (int k = 0; k < 4; ++k) sl += masks[b * T_ + lane + k * 64];
#pragma unroll
    for (int m = 32; m; m >>= 1) sl += __shfl_xor(sl, m, 64);
    const int seq_len = sl;

    const float* eb = emis + (size_t)b * (T_ * K_);

    if (bid < B_) {
        // ================= forward, delayed normalization ===================
        float Ecol[64];
#pragma unroll
        for (int i = 0; i < 64; ++i) Ecol[i] = __expf(trans[i * K_ + lane]);

        float e_c = eb[lane];
        float e00 = readlane0_f(e_c);
        float p = __expf(e_c - e00);
        float C = e00;
        float logD0prev = 0.f;
        float e_n = eb[K_ + lane];
        float en0 = readlane0_f(e_n);
        float xg = __expf(e_n - en0);

#define FWD8(base)                                                     \
            a0 = fmaf(readlane_f<base + 0>(p), Ecol[base + 0], a0);    \
            a1 = fmaf(readlane_f<base + 1>(p), Ecol[base + 1], a1);    \
            a2 = fmaf(readlane_f<base + 2>(p), Ecol[base + 2], a2);    \
            a3 = fmaf(readlane_f<base + 3>(p), Ecol[base + 3], a3);    \
            a4 = fmaf(readlane_f<base + 4>(p), Ecol[base + 4], a4);    \
            a5 = fmaf(readlane_f<base + 5>(p), Ecol[base + 5], a5);    \
            a6 = fmaf(readlane_f<base + 6>(p), Ecol[base + 6], a6);    \
            a7 = fmaf(readlane_f<base + 7>(p), Ecol[base + 7], a7);

        for (int t = 1; t < T_; ++t) {
            float e_f = (t < T_ - 1) ? eb[(t + 1) * K_ + lane] : 0.f;  // global prefetch
            float a0 = 0.f, a1 = 0.f, a2 = 0.f, a3 = 0.f;
            float a4 = 0.f, a5 = 0.f, a6 = 0.f, a7 = 0.f;
            FWD8(0) FWD8(8) FWD8(16) FWD8(24) FWD8(32) FWD8(40) FWD8(48) FWD8(56)
            float D = ((a0 + a1) + (a2 + a3)) + ((a4 + a5) + (a6 + a7));
            float pnew = D * xg;
            if (t < seq_len) { p = pnew; C += en0 + logD0prev; }
            // off-chain prep for next step
            float D0 = readlane0_f(D);
            logD0prev = __logf(D0);
            float gn = __fdividef(1.f, D0);
            en0 = readlane0_f(e_f);
            xg = __expf(e_f - en0) * gn;
            e_n = e_f;
        }
#undef FWD8
        float rs = p;
#pragma unroll
        for (int m = 32; m; m >>= 1) rs += __shfl_xor(rs, m, 64);
        float log_norm = C + __logf(rs);

        // ---------------- sequence score (global gathers, once) -------------
        float sc = 0.f;
#pragma unroll
        for (int k = 0; k < 4; ++k) {
            int t = lane + k * 64;
            if (t < seq_len) {
                int tg = target[b * T_ + t];
                sc += eb[t * K_ + tg];
                if (t >= 1) sc += trans[target[b * T_ + t - 1] * K_ + tg];
            }
        }
#pragma unroll
        for (int m = 32; m; m >>= 1) sc += __shfl_xor(sc, m, 64);
        if (lane == 0) out[BT_ + b] = sc - log_norm;
    } else {
        // ================= Viterbi: readlane max-plus =======================
        float Tcol[64];
#pragma unroll
        for (int i = 0; i < 64; ++i) Tcol[i] = trans[i * K_ + lane];
        for (int idx = lane; idx < K_ * K_; idx += 64)
            tbuf[(idx >> 6) * 65 + (idx & 63)] = trans[idx];

        float v = eb[lane];
        vbuf[lane] = v;
        float e_n = eb[K_ + lane];

#define VIT8(base)                                                        \
            m0 = fmaxf(m0, readlane_f<base + 0>(v) + Tcol[base + 0]);     \
            m1 = fmaxf(m1, readlane_f<base + 1>(v) + Tcol[base + 1]);     \
            m2 = fmaxf(m2, readlane_f<base + 2>(v) + Tcol[base + 2]);     \
            m3 = fmaxf(m3, readlane_f<base + 3>(v) + Tcol[base + 3]);     \
            m4 = fmaxf(m4, readlane_f<base + 4>(v) + Tcol[base + 4]);     \
            m5 = fmaxf(m5, readlane_f<base + 5>(v) + Tcol[base + 5]);     \
            m6 = fmaxf(m6, readlane_f<base + 6>(v) + Tcol[base + 6]);     \
            m7 = fmaxf(m7, readlane_f<base + 7>(v) + Tcol[base + 7]);

        for (int t = 1; t < T_; ++t) {
            float e_f = (t < T_ - 1) ? eb[(t + 1) * K_ + lane] : 0.f;  // global prefetch
            float m0 = -3.4e38f, m1 = m0, m2 = m0, m3 = m0;
            float m4 = m0, m5 = m0, m6 = m0, m7 = m0;
            VIT8(0) VIT8(8) VIT8(16) VIT8(24) VIT8(32) VIT8(40) VIT8(48) VIT8(56)
            float M = fmaxf(fmaxf(fmaxf(m0, m1), fmaxf(m2, m3)),
                            fmaxf(fmaxf(m4, m5), fmaxf(m6, m7)));
            float vn = M + e_n;
            if (t < seq_len) v = vn;
            vbuf[t * K_ + lane] = v;   // off-chain ds_write (history)
            e_n = e_f;
        }
#undef VIT8

        // last tag: first index of max over lanes (np.argmax tie rule)
        float M = wave_max64(v);
        unsigned long long ball = __ballot(v >= M);
        int tag = (int)__builtin_ctzll(ball);

        int path[4];
#pragma unroll
        for (int k = 0; k < 4; ++k) path[k] = 0;
        if (lane == ((T_ - 1) & 63)) path[(T_ - 1) >> 6] = tag;

        float vpre = vbuf[(T_ - 2) * K_ + lane];
        for (int t = T_ - 1; t >= 1; --t) {
            float vnext = (t >= 2) ? vbuf[(t - 2) * K_ + lane] : 0.f;
            if (t < seq_len) {
                float s = vpre + tbuf[lane * 65 + tag];
                float Ms = wave_max64(s);
                unsigned long long bl = __ballot(s >= Ms);
                tag = (int)__builtin_ctzll(bl);
            }
            int pidx = t - 1;
            if (lane == (pidx & 63)) path[pidx >> 6] = tag;
            vpre = vnext;
        }
#pragma unroll
        for (int k = 0; k < 4; ++k) {
            int t = lane + k * 64;
            out[b * T_ + t] = (t < seq_len) ? (float)path[k] : 0.f;
        }
    }
}

// ---------------------------------------------------------------------------
extern "C" void kernel_launch(void* const* d_in, const int* in_sizes, int n_in,
                              void* d_out, int out_size, void* d_ws, size_t ws_size,
                              hipStream_t stream) {
    const float* hidden = (const float*)d_in[0];
    const int* masks    = (const int*)d_in[1];
    const int* target   = (const int*)d_in[2];
    const float* W      = (const float*)d_in[3];
    const float* bias   = (const float*)d_in[4];
    const float* trans  = (const float*)d_in[5];
    float* out = (float*)d_out;
    float* emis = (float*)d_ws;

    gemm_emis<<<dim3(BT_ / 64), dim3(256), 0, stream>>>(hidden, W, bias, emis);
    crf_kernel<<<dim3(2 * B_), dim3(64), 0, stream>>>(emis, masks, target, trans, out);
}